// Round 6
// baseline (658.851 us; speedup 1.0000x reference)
//
#include <hip/hip_runtime.h>
#include <hip/hip_bf16.h>

typedef __bf16 bf16;
typedef __bf16 bf16x8 __attribute__((ext_vector_type(8)));
typedef float  f32x4  __attribute__((ext_vector_type(4)));
typedef int    i32x4  __attribute__((ext_vector_type(4)));

#define TK 32
#define FB_TM 128
#define FB_TN 128
#define LDS_PAD 40   // fallback-path row stride

// ---- async global->LDS, 16B per lane; lds base must be wave-uniform ----
typedef __attribute__((address_space(3))) void       lds_t;
typedef __attribute__((address_space(1))) const void gbl_t;
__device__ __forceinline__ void async16(const void* g, void* l) {
    __builtin_amdgcn_global_load_lds((gbl_t*)g, (lds_t*)l, 16, 0, 0);
}

// ===================== fast path: bf16 NT GEMM, 3-buffer counted-vmcnt =====
// C[m][n] = sum_k A[m][k]*B[n][k] (+bias). A,B bf16. TC in {float,bf16}.
// BIAS: 0 none, 1 bias[n], 2 bias[m]. NTC: nontemporal C stores.
//
// Geometry (r4): block 256x128, 4 waves (2M x 2N), wave tile 128x64.
// Pipeline (race-free since r2): 3 buffers, stage tile t+2 each iter
// (6 loads/thread/tile), steady-state wait vmcnt(6) = tile t complete while
// t+1 stays in flight; lgkmcnt(0) before each barrier = WAR-safe reuse.
//
// ROUND-6: manual 3x unroll of the K-loop so the buffer-rotation offsets
// (oC/oS) are compile-time literals. r0 counters showed VALUBusy 43.7% >
// MfmaUtil 22.7%: runtime-rotated offsets forced per-iteration VALU address
// recompute for all 12 ds_reads + 6 stage destinations. With literals the
// compiler folds offsets into ds_read offset immediates. Each unrolled
// instance is textually the verified iteration; sync structure unchanged.
// Micro-reorder: ds_reads issue before stage() so LDS latency drains under
// the staging address math (schedule-only).

#define GEMM_ITER(TT, OC, OS_)                                                  \
    do {                                                                        \
        if ((TT) < NT_ - 1)                                                     \
            asm volatile("s_waitcnt vmcnt(6) lgkmcnt(0)" ::: "memory");         \
        else                                                                    \
            asm volatile("s_waitcnt vmcnt(0) lgkmcnt(0)" ::: "memory");         \
        __builtin_amdgcn_s_barrier();                                           \
        __builtin_amdgcn_sched_barrier(0);                                      \
        bf16x8 af[8], bfr[4];                                                   \
        _Pragma("unroll")                                                       \
        for (int i = 0; i < 8; ++i)                                             \
            af[i] = *(bf16x8*)&lds[(OC) + (wm + i * 16 + lrow) * TK + quad * 8];\
        _Pragma("unroll")                                                       \
        for (int j = 0; j < 4; ++j)                                             \
            bfr[j] = *(bf16x8*)&lds[(OC) + ASZ + (wn + j * 16 + lrow) * TK      \
                                    + quad * 8];                                \
        if ((TT) + 2 < NT_) stage((TT) + 2, (OS_));                             \
        _Pragma("unroll")                                                       \
        for (int i = 0; i < 8; ++i)                                             \
            _Pragma("unroll")                                                   \
            for (int j = 0; j < 4; ++j)                                         \
                acc[i][j] = __builtin_amdgcn_mfma_f32_16x16x32_bf16(            \
                    af[i], bfr[j], acc[i][j], 0, 0, 0);                         \
    } while (0)

template<typename TC, int BIAS, int NTC>
__global__ __launch_bounds__(256, 2)
void gemm_bt(const bf16* __restrict__ A, const bf16* __restrict__ B,
             TC* __restrict__ C, const float* __restrict__ bias,
             int K, int lda, int ldb, int ldc,
             long sA, long sB, long sC)
{
    constexpr int BM  = 256, BN = 128;
    constexpr int ASZ = BM * TK;          // 8192 elems (16 KB)
    constexpr int BSZ = BN * TK;          // 4096 elems (8 KB)
    constexpr int BUFE = ASZ + BSZ;       // 12288 elems (24 KB)
    __shared__ bf16 lds[3 * BUFE];        // 72 KB -> 2 blocks/CU (8 waves)

    // XCD-aware chunked swizzle (every launch below has nwg % 8 == 0)
    const int gx = gridDim.x, gy = gridDim.y;
    int lin = blockIdx.x + gx * (blockIdx.y + gy * blockIdx.z);
    const int cpx = (gx * gy * gridDim.z) >> 3;
    lin = (lin & 7) * cpx + (lin >> 3);
    const int bx  = lin % gx;
    const int rem = lin / gx;
    const int by  = rem % gy;
    const int bz  = rem / gy;

    A += (long)bz * sA;  B += (long)bz * sB;  C += (long)bz * sC;

    const int m0 = by * BM;
    const int n0 = bx * BN;

    const int t    = threadIdx.x;
    const int lane = t & 63;
    const int wave = t >> 6;
    const int wm   = (wave >> 1) * 128;  // wave's 128x64 output tile
    const int wn   = (wave & 1) * 64;
    const int lrow = lane & 15;
    const int quad = lane >> 4;

    const int srow = lane >> 2;          // staging: row within 16-row group
    const int scol = (lane & 3) * 8;     // staging: elem offset (16B chunks)

    // per-thread staging base pointers (each async16: wave = 16 rows x 64B)
    const bf16* pA = &A[(long)(m0 + wave * 16 + srow) * lda + scol];
    const bf16* pB = &B[(long)(n0 + wave * 16 + srow) * ldb + scol];

    const int NT_ = K / TK;

    // A: 256 rows = 16 groups; 4 waves x 4 asyncs. B: 128 rows = 8 groups;
    // 4 waves x 2 asyncs. 6 loads/thread/tile, fixed issue order.
    auto stage = [&](int tile, int oS) {
        const int k0 = tile * TK;
        #pragma unroll
        for (int j = 0; j < 4; ++j)
            async16(pA + (long)(j * 64) * lda + k0,
                    &lds[oS + (wave * 16 + j * 64) * TK]);
        #pragma unroll
        for (int j = 0; j < 2; ++j)
            async16(pB + (long)(j * 64) * ldb + k0,
                    &lds[oS + ASZ + (wave * 16 + j * 64) * TK]);
    };

    // prologue: tiles 0 and 1 in flight; pin region boundary so
    // "oldest 6" == tile tt at each vmcnt.
    stage(0, 0);
    asm volatile("" ::: "memory");
    stage(1, BUFE);

    f32x4 acc[8][4] = {};

    // 3x-unrolled main loop: rotation phase is 0 at loop entry and exit,
    // so the <=2 remainder iterations always start at offsets (0, 2*BUFE).
    int tt = 0;
    for (; tt + 3 <= NT_; tt += 3) {
        GEMM_ITER(tt,     0,        2 * BUFE);
        GEMM_ITER(tt + 1, BUFE,     0);
        GEMM_ITER(tt + 2, 2 * BUFE, BUFE);
    }
    if (tt < NT_) { GEMM_ITER(tt, 0,    2 * BUFE); ++tt; }
    if (tt < NT_) { GEMM_ITER(tt, BUFE, 0);        ++tt; }

    // epilogue: C/D layout col = lane&15, row = quad*4 + reg
    #pragma unroll
    for (int i = 0; i < 8; ++i) {
        #pragma unroll
        for (int j = 0; j < 4; ++j) {
            #pragma unroll
            for (int r = 0; r < 4; ++r) {
                const int row = m0 + wm + i * 16 + quad * 4 + r;
                const int col = n0 + wn + j * 16 + lrow;
                float v = acc[i][j][r];
                if (BIAS == 1) v += bias[col];
                if (BIAS == 2) v += bias[row];
                if constexpr (NTC)
                    __builtin_nontemporal_store((TC)v, &C[(long)row * ldc + col]);
                else
                    C[(long)row * ldc + col] = (TC)v;
            }
        }
    }
}

// fp32 -> bf16 elementwise, 8 elems/thread; grid sized exactly (n % 2048 == 0)
__global__ __launch_bounds__(256)
void cvt_f32_bf16(const float* __restrict__ x, bf16* __restrict__ y)
{
    const long i = ((long)blockIdx.x * 256 + threadIdx.x) * 8;
    const f32x4 a = __builtin_nontemporal_load((const f32x4*)(x + i));
    const f32x4 b = __builtin_nontemporal_load((const f32x4*)(x + i + 4));
    bf16x8 v;
    v[0] = (bf16)a[0]; v[1] = (bf16)a[1]; v[2] = (bf16)a[2]; v[3] = (bf16)a[3];
    v[4] = (bf16)b[0]; v[5] = (bf16)b[1]; v[6] = (bf16)b[2]; v[7] = (bf16)b[3];
    *(bf16x8*)(y + i) = v;   // re-read soon by GEMMs -> keep cached
}

// ===================== fallback path: fp32/bf16 manual staging GEMM ========
template<typename T>
__device__ inline void stage8(bf16* dst, const T* src) {
    if constexpr (sizeof(T) == 4) {
        const float4 f0 = *(const float4*)src;
        const float4 f1 = *(const float4*)(src + 4);
        bf16x8 v;
        v[0] = (bf16)f0.x; v[1] = (bf16)f0.y; v[2] = (bf16)f0.z; v[3] = (bf16)f0.w;
        v[4] = (bf16)f1.x; v[5] = (bf16)f1.y; v[6] = (bf16)f1.z; v[7] = (bf16)f1.w;
        *(bf16x8*)dst = v;
    } else {
        *(uint4*)dst = *(const uint4*)src;
    }
}

template<typename TA, typename TB, typename TC, int BIAS>
__global__ __launch_bounds__(256)
void gemm_nt(const TA* __restrict__ A, const TB* __restrict__ B,
             TC* __restrict__ C, const float* __restrict__ bias,
             int K, int lda, int ldb, int ldc,
             long sA, long sB, long sC)
{
    __shared__ bf16 lsA[FB_TM * LDS_PAD];
    __shared__ bf16 lsB[FB_TN * LDS_PAD];

    const int bz = blockIdx.z;
    A += (long)bz * sA;  B += (long)bz * sB;  C += (long)bz * sC;

    const int m0 = blockIdx.y * FB_TM;
    const int n0 = blockIdx.x * FB_TN;

    const int t    = threadIdx.x;
    const int lane = t & 63;
    const int wave = t >> 6;
    const int wm   = (wave >> 1) * 64;
    const int wn   = (wave & 1) * 64;
    const int lrow = lane & 15;
    const int quad = lane >> 4;
    const int sr = t >> 2;
    const int sk = (t & 3) * 8;

    f32x4 acc[4][4] = {};

    for (int k0 = 0; k0 < K; k0 += TK) {
        __syncthreads();
        #pragma unroll
        for (int h = 0; h < 2; ++h) {
            const int row = h * 64 + sr;
            stage8(&lsA[row * LDS_PAD + sk], &A[(long)(m0 + row) * lda + k0 + sk]);
            stage8(&lsB[row * LDS_PAD + sk], &B[(long)(n0 + row) * ldb + k0 + sk]);
        }
        __syncthreads();

        bf16x8 af[4], bfr[4];
        #pragma unroll
        for (int i = 0; i < 4; ++i)
            af[i] = *(bf16x8*)&lsA[(wm + i * 16 + lrow) * LDS_PAD + quad * 8];
        #pragma unroll
        for (int j = 0; j < 4; ++j)
            bfr[j] = *(bf16x8*)&lsB[(wn + j * 16 + lrow) * LDS_PAD + quad * 8];

        #pragma unroll
        for (int i = 0; i < 4; ++i)
            #pragma unroll
            for (int j = 0; j < 4; ++j)
                acc[i][j] = __builtin_amdgcn_mfma_f32_16x16x32_bf16(
                    af[i], bfr[j], acc[i][j], 0, 0, 0);
    }

    #pragma unroll
    for (int i = 0; i < 4; ++i) {
        #pragma unroll
        for (int j = 0; j < 4; ++j) {
            #pragma unroll
            for (int r = 0; r < 4; ++r) {
                const int row = m0 + wm + i * 16 + quad * 4 + r;
                const int col = n0 + wn + j * 16 + lrow;
                float v = acc[i][j][r];
                if (BIAS == 1) v += bias[col];
                if (BIAS == 2) v += bias[row];
                C[(long)row * ldc + col] = (TC)v;
            }
        }
    }
}

// ===================== softmax (optional bf16 dual write) ==================
// Raw score is L3-resident (written cached by QK) -> normal loads. Mask is
// cold/once -> nt load. Final score & never-re-read streams -> nt store.
template<int DUAL>
__global__ __launch_bounds__(256)
void softmax_rows(float* __restrict__ score, const int* __restrict__ mask,
                  bf16* __restrict__ pb)
{
    const int t = threadIdx.x;
    const long base = (long)blockIdx.x * 2048 + t * 8;

    const f32x4 a0 = *(const f32x4*)(score + base);
    const f32x4 a1 = *(const f32x4*)(score + base + 4);
    const i32x4 mA = __builtin_nontemporal_load((const i32x4*)(mask + base));
    const i32x4 mB = __builtin_nontemporal_load((const i32x4*)(mask + base + 4));

    const float INV = 0.03125f;  // 1/sqrt(1024)
    float s[8];
    #pragma unroll
    for (int i = 0; i < 4; ++i) s[i]     = mA[i] ? a0[i] * INV : -INFINITY;
    #pragma unroll
    for (int i = 0; i < 4; ++i) s[4 + i] = mB[i] ? a1[i] * INV : -INFINITY;

    float mx = s[0];
    #pragma unroll
    for (int i = 1; i < 8; ++i) mx = fmaxf(mx, s[i]);
    #pragma unroll
    for (int o = 32; o > 0; o >>= 1) mx = fmaxf(mx, __shfl_xor(mx, o, 64));

    __shared__ float redm[4], reds[4];
    const int wave = t >> 6, lane = t & 63;
    if (lane == 0) redm[wave] = mx;
    __syncthreads();
    mx = fmaxf(fmaxf(redm[0], redm[1]), fmaxf(redm[2], redm[3]));

    const bool dead = !(mx > -INFINITY);
    float e[8], sum = 0.f;
    #pragma unroll
    for (int i = 0; i < 8; ++i) {
        const float x = dead ? 0.0f : __expf(s[i] - mx);
        e[i] = x;
        sum += x;
    }
    #pragma unroll
    for (int o = 32; o > 0; o >>= 1) sum += __shfl_xor(sum, o, 64);
    if (lane == 0) reds[wave] = sum;
    __syncthreads();
    sum = reds[0] + reds[1] + reds[2] + reds[3];

    const float inv = dead ? 0.0f : (1.0f / sum);
    f32x4 o0, o1;
    float p[8];
    #pragma unroll
    for (int i = 0; i < 8; ++i) p[i] = e[i] * inv;
    o0[0] = p[0]; o0[1] = p[1]; o0[2] = p[2]; o0[3] = p[3];
    o1[0] = p[4]; o1[1] = p[5]; o1[2] = p[6]; o1[3] = p[7];

    __builtin_nontemporal_store(o0, (f32x4*)(score + base));
    __builtin_nontemporal_store(o1, (f32x4*)(score + base + 4));
    if (DUAL) {
        bf16x8 v;
        #pragma unroll
        for (int i = 0; i < 8; ++i) v[i] = (bf16)p[i];
        *(bf16x8*)(pb + base) = v;   // re-read by PV -> keep cached
    }
}

extern "C" void kernel_launch(void* const* d_in, const int* in_sizes, int n_in,
                              void* d_out, int out_size, void* d_ws, size_t ws_size,
                              hipStream_t stream)
{
    const float* key   = (const float*)d_in[0];   // [8,2048,1024]
    const float* query = (const float*)d_in[1];   // [8,2048,1024]
    const int*   mask  = (const int*)d_in[2];     // [8,2048,2048]
    const float* Wq = (const float*)d_in[3];
    const float* bq = (const float*)d_in[4];
    const float* Wk = (const float*)d_in[5];
    const float* bk = (const float*)d_in[6];
    const float* Wv = (const float*)d_in[7];
    const float* bv = (const float*)d_in[8];

    float* out   = (float*)d_out;                      // [8,2048,1024]
    float* score = out + (size_t)8 * 2048 * 1024;      // [8,2048,2048]

    const dim3 blk(256, 1, 1);
    const long SB = (long)2048 * 1024;
    const long SS = (long)2048 * 2048;
    const size_t NX = (size_t)8 * 2048 * 1024;         // 16.8M elems
    const size_t NW = (size_t)1024 * 1024;

    // fast-path ws layout (bf16 elems): xb | qb | kb | vt | wq | wk | wv
    // Pb (32M elems) aliases [xb qb] (both dead by softmax time).
    const size_t NEED = (4 * NX + 3 * NW) * sizeof(bf16);

    if (ws_size >= NEED) {
        bf16* xb = (bf16*)d_ws;
        bf16* qb = xb + NX;
        bf16* kb = qb + NX;
        bf16* vt = kb + NX;
        bf16* wq = vt + NX;
        bf16* wk = wq + NW;
        bf16* wv = wk + NW;
        bf16* Pb = xb;                                  // alias over xb+qb

        cvt_f32_bf16<<<dim3(NW / 2048), blk, 0, stream>>>(Wq, wq);
        cvt_f32_bf16<<<dim3(NW / 2048), blk, 0, stream>>>(Wk, wk);
        cvt_f32_bf16<<<dim3(NW / 2048), blk, 0, stream>>>(Wv, wv);

        // key -> xb; then k-projection and v^T (both consume xb)
        // grids: BM=256 (y), BN=128 (x)
        cvt_f32_bf16<<<dim3(NX / 2048), blk, 0, stream>>>(key, xb);
        gemm_bt<bf16, 1, 0><<<dim3(8, 64, 1), blk, 0, stream>>>(
            xb, wk, kb, bk, 1024, 1024, 1024, 1024, 0, 0, 0);
        gemm_bt<bf16, 2, 0><<<dim3(16, 4, 8), blk, 0, stream>>>(
            wv, xb, vt, bv, 1024, 1024, 1024, 2048, 0, SB, SB);

        // query -> xb (reuse); q-projection
        cvt_f32_bf16<<<dim3(NX / 2048), blk, 0, stream>>>(query, xb);
        gemm_bt<bf16, 1, 0><<<dim3(8, 64, 1), blk, 0, stream>>>(
            xb, wq, qb, bq, 1024, 1024, 1024, 1024, 0, 0, 0);

        // raw scores fp32 -> cached stores (softmax re-reads from L3)
        gemm_bt<float, 0, 0><<<dim3(16, 8, 8), blk, 0, stream>>>(
            qb, kb, score, nullptr, 1024, 1024, 1024, 2048, SB, SB, SS);

        // masked softmax: fp32 in place + bf16 copy to Pb
        softmax_rows<1><<<dim3(16384), blk, 0, stream>>>(score, mask, Pb);

        // O = P . vt (out is final output -> nt stores)
        gemm_bt<float, 0, 1><<<dim3(8, 8, 8), blk, 0, stream>>>(
            Pb, vt, out, nullptr, 2048, 2048, 2048, 1024, SS, SB, SB);
    } else {
        // fallback: round-2 passing path (fp32 staging, 100.7 MB ws)
        bf16* qb = (bf16*)d_ws;
        bf16* kb = qb + NX;
        bf16* vt = kb + NX;

        gemm_nt<float, float, bf16, 1><<<dim3(8, 128, 1), blk, 0, stream>>>(
            query, Wq, qb, bq, 1024, 1024, 1024, 1024, 0, 0, 0);
        gemm_nt<float, float, bf16, 1><<<dim3(8, 128, 1), blk, 0, stream>>>(
            key, Wk, kb, bk, 1024, 1024, 1024, 1024, 0, 0, 0);
        gemm_nt<float, float, bf16, 2><<<dim3(16, 8, 8), blk, 0, stream>>>(
            Wv, key, vt, bv, 1024, 1024, 1024, 2048, 0, SB, SB);
        gemm_nt<bf16, bf16, float, 0><<<dim3(16, 16, 8), blk, 0, stream>>>(
            qb, kb, score, nullptr, 1024, 1024, 1024, 2048, SB, SB, SS);
        softmax_rows<0><<<dim3(16384), blk, 0, stream>>>(score, mask, nullptr);
        gemm_nt<float, bf16, float, 0><<<dim3(8, 16, 8), blk, 0, stream>>>(
            score, vt, out, nullptr, 2048, 2048, 2048, 1024, SS, SB, SB);
    }
}

// Round 7
// 647.300 us; speedup vs baseline: 1.0178x; 1.0178x over previous
//
#include <hip/hip_runtime.h>
#include <hip/hip_bf16.h>

typedef __bf16 bf16;
typedef __bf16 bf16x8 __attribute__((ext_vector_type(8)));
typedef float  f32x4  __attribute__((ext_vector_type(4)));
typedef int    i32x4  __attribute__((ext_vector_type(4)));

#define TK 32
#define FB_TM 128
#define FB_TN 128
#define LDS_PAD 40   // fallback-path row stride

// ---- async global->LDS, 16B per lane; lds base must be wave-uniform ----
typedef __attribute__((address_space(3))) void       lds_t;
typedef __attribute__((address_space(1))) const void gbl_t;
__device__ __forceinline__ void async16(const void* g, void* l) {
    __builtin_amdgcn_global_load_lds((gbl_t*)g, (lds_t*)l, 16, 0, 0);
}

// ===================== fast path: bf16 NT GEMM, 2-phase K-step =============
// C[m][n] = sum_k A[m][k]*B[n][k] (+bias). A,B bf16. TC in {float,bf16}.
// BIAS: 0 none, 1 bias[n], 2 bias[m]. NTC: nontemporal C stores.
//
// Geometry (r4): block 256x128, 4 waves (2M x 2N), wave tile 128x64.
// Pipeline skeleton (race-free since r2): 3 buffers, stage tile t+2 each
// K-step (6 loads/thread), opening wait vmcnt(6)=tile t landed while t+1
// stays in flight (never 0 mid-loop); lgkmcnt(0) before the opening barrier
// = WAR-safe buffer reuse.
//
// ROUND-7: 8-phase-template phase anatomy (T3 rhythm + T5) inside the
// verified skeleton. Each K-step = 2 phases of exactly 16 MFMAs:
//   P0: ds_read A0-3+B0-3 || stage 3 loads; barrier; lgkm(0); setprio(1);
//       16 MFMA; setprio(0); barrier
//   P1: ds_read A4-7      || stage 3 loads; barrier; lgkm(0); setprio(1);
//       16 MFMA; setprio(0)   (next step's opening barrier closes P1)
// B-frags persist in registers across P1. Invariants unchanged: every
// wave's reads of the buffer being overwritten are retired by its own
// lgkm(0) before the opening barrier; stage FIFO stays 6/step.
// sched_barrier(0) after each lgkm(0) per rule #18 (MFMA hoist hazard).
template<typename TC, int BIAS, int NTC>
__global__ __launch_bounds__(256, 2)
void gemm_bt(const bf16* __restrict__ A, const bf16* __restrict__ B,
             TC* __restrict__ C, const float* __restrict__ bias,
             int K, int lda, int ldb, int ldc,
             long sA, long sB, long sC)
{
    constexpr int BM  = 256, BN = 128;
    constexpr int ASZ = BM * TK;          // 8192 elems (16 KB)
    constexpr int BSZ = BN * TK;          // 4096 elems (8 KB)
    constexpr int BUFE = ASZ + BSZ;       // 12288 elems (24 KB)
    __shared__ bf16 lds[3 * BUFE];        // 72 KB -> 2 blocks/CU (8 waves)

    // XCD-aware chunked swizzle (every launch below has nwg % 8 == 0)
    const int gx = gridDim.x, gy = gridDim.y;
    int lin = blockIdx.x + gx * (blockIdx.y + gy * blockIdx.z);
    const int cpx = (gx * gy * gridDim.z) >> 3;
    lin = (lin & 7) * cpx + (lin >> 3);
    const int bx  = lin % gx;
    const int rem = lin / gx;
    const int by  = rem % gy;
    const int bz  = rem / gy;

    A += (long)bz * sA;  B += (long)bz * sB;  C += (long)bz * sC;

    const int m0 = by * BM;
    const int n0 = bx * BN;

    const int t    = threadIdx.x;
    const int lane = t & 63;
    const int wave = t >> 6;
    const int wm   = (wave >> 1) * 128;  // wave's 128x64 output tile
    const int wn   = (wave & 1) * 64;
    const int lrow = lane & 15;
    const int quad = lane >> 4;

    const int srow = lane >> 2;          // staging: row within 16-row group
    const int scol = (lane & 3) * 8;     // staging: elem offset (16B chunks)

    // per-thread staging base pointers (each async16: wave = 16 rows x 64B)
    const bf16* pA = &A[(long)(m0 + wave * 16 + srow) * lda + scol];
    const bf16* pB = &B[(long)(n0 + wave * 16 + srow) * ldb + scol];

    const int NT_ = K / TK;

    // A: 256 rows = 16 groups (4 waves x 4 asyncs), B: 128 rows = 8 groups
    // (4 waves x 2 asyncs). Split 3 + 3 with fixed issue order so the
    // 6-loads/K-step vmcnt FIFO arithmetic is unchanged.
    auto stage3a = [&](int tile, int oS) {
        const int k0 = tile * TK;
        #pragma unroll
        for (int j = 0; j < 3; ++j)
            async16(pA + (long)(j * 64) * lda + k0,
                    &lds[oS + (wave * 16 + j * 64) * TK]);
    };
    auto stage3b = [&](int tile, int oS) {
        const int k0 = tile * TK;
        async16(pA + (long)(3 * 64) * lda + k0,
                &lds[oS + (wave * 16 + 3 * 64) * TK]);
        #pragma unroll
        for (int j = 0; j < 2; ++j)
            async16(pB + (long)(j * 64) * ldb + k0,
                    &lds[oS + ASZ + (wave * 16 + j * 64) * TK]);
    };

    // prologue: tiles 0 and 1 in flight; pin region boundaries so
    // "oldest 6" == tile tt at each opening vmcnt.
    stage3a(0, 0); stage3b(0, 0);
    asm volatile("" ::: "memory");
    stage3a(1, BUFE); stage3b(1, BUFE);

    int oC = 0, oN = BUFE, oS = 2 * BUFE;
    f32x4 acc[8][4] = {};

    for (int tt = 0; tt < NT_; ++tt) {
        // opening: tile tt landed (vmcnt), this wave's previous reads done
        // (lgkm) -> stage into oS below is WAR-safe after the barrier.
        if (tt < NT_ - 1) asm volatile("s_waitcnt vmcnt(6) lgkmcnt(0)" ::: "memory");
        else              asm volatile("s_waitcnt vmcnt(0) lgkmcnt(0)" ::: "memory");
        __builtin_amdgcn_s_barrier();
        __builtin_amdgcn_sched_barrier(0);

        bf16x8 af[8], bfr[4];

        // ---- phase 0: A0-3 + B0-3 reads || stage chunk a ----
        #pragma unroll
        for (int i = 0; i < 4; ++i)
            af[i] = *(bf16x8*)&lds[oC + (wm + i * 16 + lrow) * TK + quad * 8];
        #pragma unroll
        for (int j = 0; j < 4; ++j)
            bfr[j] = *(bf16x8*)&lds[oC + ASZ + (wn + j * 16 + lrow) * TK + quad * 8];
        if (tt + 2 < NT_) stage3a(tt + 2, oS);
        __builtin_amdgcn_sched_barrier(0);
        __builtin_amdgcn_s_barrier();
        asm volatile("s_waitcnt lgkmcnt(0)" ::: "memory");
        __builtin_amdgcn_sched_barrier(0);   // rule #18: no MFMA hoist
        __builtin_amdgcn_s_setprio(1);
        #pragma unroll
        for (int i = 0; i < 4; ++i)
            #pragma unroll
            for (int j = 0; j < 4; ++j)
                acc[i][j] = __builtin_amdgcn_mfma_f32_16x16x32_bf16(
                    af[i], bfr[j], acc[i][j], 0, 0, 0);
        __builtin_amdgcn_s_setprio(0);
        __builtin_amdgcn_sched_barrier(0);
        __builtin_amdgcn_s_barrier();

        // ---- phase 1: A4-7 reads || stage chunk b (B regs persist) ----
        #pragma unroll
        for (int i = 4; i < 8; ++i)
            af[i] = *(bf16x8*)&lds[oC + (wm + i * 16 + lrow) * TK + quad * 8];
        if (tt + 2 < NT_) stage3b(tt + 2, oS);
        __builtin_amdgcn_sched_barrier(0);
        __builtin_amdgcn_s_barrier();
        asm volatile("s_waitcnt lgkmcnt(0)" ::: "memory");
        __builtin_amdgcn_sched_barrier(0);
        __builtin_amdgcn_s_setprio(1);
        #pragma unroll
        for (int i = 4; i < 8; ++i)
            #pragma unroll
            for (int j = 0; j < 4; ++j)
                acc[i][j] = __builtin_amdgcn_mfma_f32_16x16x32_bf16(
                    af[i], bfr[j], acc[i][j], 0, 0, 0);
        __builtin_amdgcn_s_setprio(0);
        // next step's opening waitcnt+barrier closes phase 1

        const int tmp = oC; oC = oN; oN = oS; oS = tmp;   // rotate buffers
    }

    // epilogue: C/D layout col = lane&15, row = quad*4 + reg
    #pragma unroll
    for (int i = 0; i < 8; ++i) {
        #pragma unroll
        for (int j = 0; j < 4; ++j) {
            #pragma unroll
            for (int r = 0; r < 4; ++r) {
                const int row = m0 + wm + i * 16 + quad * 4 + r;
                const int col = n0 + wn + j * 16 + lrow;
                float v = acc[i][j][r];
                if (BIAS == 1) v += bias[col];
                if (BIAS == 2) v += bias[row];
                if constexpr (NTC)
                    __builtin_nontemporal_store((TC)v, &C[(long)row * ldc + col]);
                else
                    C[(long)row * ldc + col] = (TC)v;
            }
        }
    }
}

// fp32 -> bf16 elementwise, 8 elems/thread; grid sized exactly (n % 2048 == 0)
__global__ __launch_bounds__(256)
void cvt_f32_bf16(const float* __restrict__ x, bf16* __restrict__ y)
{
    const long i = ((long)blockIdx.x * 256 + threadIdx.x) * 8;
    const f32x4 a = __builtin_nontemporal_load((const f32x4*)(x + i));
    const f32x4 b = __builtin_nontemporal_load((const f32x4*)(x + i + 4));
    bf16x8 v;
    v[0] = (bf16)a[0]; v[1] = (bf16)a[1]; v[2] = (bf16)a[2]; v[3] = (bf16)a[3];
    v[4] = (bf16)b[0]; v[5] = (bf16)b[1]; v[6] = (bf16)b[2]; v[7] = (bf16)b[3];
    *(bf16x8*)(y + i) = v;   // re-read soon by GEMMs -> keep cached
}

// three weight tensors in one launch (saves 2 launch gaps)
__global__ __launch_bounds__(256)
void cvt3_f32_bf16(const float* __restrict__ x0, bf16* __restrict__ y0,
                   const float* __restrict__ x1, bf16* __restrict__ y1,
                   const float* __restrict__ x2, bf16* __restrict__ y2)
{
    const int which = blockIdx.y;
    const float* x = which == 0 ? x0 : (which == 1 ? x1 : x2);
    bf16*       y = which == 0 ? y0 : (which == 1 ? y1 : y2);
    const long i = ((long)blockIdx.x * 256 + threadIdx.x) * 8;
    const f32x4 a = __builtin_nontemporal_load((const f32x4*)(x + i));
    const f32x4 b = __builtin_nontemporal_load((const f32x4*)(x + i + 4));
    bf16x8 v;
    v[0] = (bf16)a[0]; v[1] = (bf16)a[1]; v[2] = (bf16)a[2]; v[3] = (bf16)a[3];
    v[4] = (bf16)b[0]; v[5] = (bf16)b[1]; v[6] = (bf16)b[2]; v[7] = (bf16)b[3];
    *(bf16x8*)(y + i) = v;
}

// ===================== fallback path: fp32/bf16 manual staging GEMM ========
template<typename T>
__device__ inline void stage8(bf16* dst, const T* src) {
    if constexpr (sizeof(T) == 4) {
        const float4 f0 = *(const float4*)src;
        const float4 f1 = *(const float4*)(src + 4);
        bf16x8 v;
        v[0] = (bf16)f0.x; v[1] = (bf16)f0.y; v[2] = (bf16)f0.z; v[3] = (bf16)f0.w;
        v[4] = (bf16)f1.x; v[5] = (bf16)f1.y; v[6] = (bf16)f1.z; v[7] = (bf16)f1.w;
        *(bf16x8*)dst = v;
    } else {
        *(uint4*)dst = *(const uint4*)src;
    }
}

template<typename TA, typename TB, typename TC, int BIAS>
__global__ __launch_bounds__(256)
void gemm_nt(const TA* __restrict__ A, const TB* __restrict__ B,
             TC* __restrict__ C, const float* __restrict__ bias,
             int K, int lda, int ldb, int ldc,
             long sA, long sB, long sC)
{
    __shared__ bf16 lsA[FB_TM * LDS_PAD];
    __shared__ bf16 lsB[FB_TN * LDS_PAD];

    const int bz = blockIdx.z;
    A += (long)bz * sA;  B += (long)bz * sB;  C += (long)bz * sC;

    const int m0 = blockIdx.y * FB_TM;
    const int n0 = blockIdx.x * FB_TN;

    const int t    = threadIdx.x;
    const int lane = t & 63;
    const int wave = t >> 6;
    const int wm   = (wave >> 1) * 64;
    const int wn   = (wave & 1) * 64;
    const int lrow = lane & 15;
    const int quad = lane >> 4;
    const int sr = t >> 2;
    const int sk = (t & 3) * 8;

    f32x4 acc[4][4] = {};

    for (int k0 = 0; k0 < K; k0 += TK) {
        __syncthreads();
        #pragma unroll
        for (int h = 0; h < 2; ++h) {
            const int row = h * 64 + sr;
            stage8(&lsA[row * LDS_PAD + sk], &A[(long)(m0 + row) * lda + k0 + sk]);
            stage8(&lsB[row * LDS_PAD + sk], &B[(long)(n0 + row) * ldb + k0 + sk]);
        }
        __syncthreads();

        bf16x8 af[4], bfr[4];
        #pragma unroll
        for (int i = 0; i < 4; ++i)
            af[i] = *(bf16x8*)&lsA[(wm + i * 16 + lrow) * LDS_PAD + quad * 8];
        #pragma unroll
        for (int j = 0; j < 4; ++j)
            bfr[j] = *(bf16x8*)&lsB[(wn + j * 16 + lrow) * LDS_PAD + quad * 8];

        #pragma unroll
        for (int i = 0; i < 4; ++i)
            #pragma unroll
            for (int j = 0; j < 4; ++j)
                acc[i][j] = __builtin_amdgcn_mfma_f32_16x16x32_bf16(
                    af[i], bfr[j], acc[i][j], 0, 0, 0);
    }

    #pragma unroll
    for (int i = 0; i < 4; ++i) {
        #pragma unroll
        for (int j = 0; j < 4; ++j) {
            #pragma unroll
            for (int r = 0; r < 4; ++r) {
                const int row = m0 + wm + i * 16 + quad * 4 + r;
                const int col = n0 + wn + j * 16 + lrow;
                float v = acc[i][j][r];
                if (BIAS == 1) v += bias[col];
                if (BIAS == 2) v += bias[row];
                C[(long)row * ldc + col] = (TC)v;
            }
        }
    }
}

// ===================== softmax (optional bf16 dual write) ==================
// Raw score is L3-resident (written cached by QK) -> normal loads. Mask is
// cold/once -> nt load. Final score & never-re-read streams -> nt store.
template<int DUAL>
__global__ __launch_bounds__(256)
void softmax_rows(float* __restrict__ score, const int* __restrict__ mask,
                  bf16* __restrict__ pb)
{
    const int t = threadIdx.x;
    const long base = (long)blockIdx.x * 2048 + t * 8;

    const f32x4 a0 = *(const f32x4*)(score + base);
    const f32x4 a1 = *(const f32x4*)(score + base + 4);
    const i32x4 mA = __builtin_nontemporal_load((const i32x4*)(mask + base));
    const i32x4 mB = __builtin_nontemporal_load((const i32x4*)(mask + base + 4));

    const float INV = 0.03125f;  // 1/sqrt(1024)
    float s[8];
    #pragma unroll
    for (int i = 0; i < 4; ++i) s[i]     = mA[i] ? a0[i] * INV : -INFINITY;
    #pragma unroll
    for (int i = 0; i < 4; ++i) s[4 + i] = mB[i] ? a1[i] * INV : -INFINITY;

    float mx = s[0];
    #pragma unroll
    for (int i = 1; i < 8; ++i) mx = fmaxf(mx, s[i]);
    #pragma unroll
    for (int o = 32; o > 0; o >>= 1) mx = fmaxf(mx, __shfl_xor(mx, o, 64));

    __shared__ float redm[4], reds[4];
    const int wave = t >> 6, lane = t & 63;
    if (lane == 0) redm[wave] = mx;
    __syncthreads();
    mx = fmaxf(fmaxf(redm[0], redm[1]), fmaxf(redm[2], redm[3]));

    const bool dead = !(mx > -INFINITY);
    float e[8], sum = 0.f;
    #pragma unroll
    for (int i = 0; i < 8; ++i) {
        const float x = dead ? 0.0f : __expf(s[i] - mx);
        e[i] = x;
        sum += x;
    }
    #pragma unroll
    for (int o = 32; o > 0; o >>= 1) sum += __shfl_xor(sum, o, 64);
    if (lane == 0) reds[wave] = sum;
    __syncthreads();
    sum = reds[0] + reds[1] + reds[2] + reds[3];

    const float inv = dead ? 0.0f : (1.0f / sum);
    f32x4 o0, o1;
    float p[8];
    #pragma unroll
    for (int i = 0; i < 8; ++i) p[i] = e[i] * inv;
    o0[0] = p[0]; o0[1] = p[1]; o0[2] = p[2]; o0[3] = p[3];
    o1[0] = p[4]; o1[1] = p[5]; o1[2] = p[6]; o1[3] = p[7];

    __builtin_nontemporal_store(o0, (f32x4*)(score + base));
    __builtin_nontemporal_store(o1, (f32x4*)(score + base + 4));
    if (DUAL) {
        bf16x8 v;
        #pragma unroll
        for (int i = 0; i < 8; ++i) v[i] = (bf16)p[i];
        *(bf16x8*)(pb + base) = v;   // re-read by PV -> keep cached
    }
}

extern "C" void kernel_launch(void* const* d_in, const int* in_sizes, int n_in,
                              void* d_out, int out_size, void* d_ws, size_t ws_size,
                              hipStream_t stream)
{
    const float* key   = (const float*)d_in[0];   // [8,2048,1024]
    const float* query = (const float*)d_in[1];   // [8,2048,1024]
    const int*   mask  = (const int*)d_in[2];     // [8,2048,2048]
    const float* Wq = (const float*)d_in[3];
    const float* bq = (const float*)d_in[4];
    const float* Wk = (const float*)d_in[5];
    const float* bk = (const float*)d_in[6];
    const float* Wv = (const float*)d_in[7];
    const float* bv = (const float*)d_in[8];

    float* out   = (float*)d_out;                      // [8,2048,1024]
    float* score = out + (size_t)8 * 2048 * 1024;      // [8,2048,2048]

    const dim3 blk(256, 1, 1);
    const long SB = (long)2048 * 1024;
    const long SS = (long)2048 * 2048;
    const size_t NX = (size_t)8 * 2048 * 1024;         // 16.8M elems
    const size_t NW = (size_t)1024 * 1024;

    // fast-path ws layout (bf16 elems): xb | qb | kb | vt | wq | wk | wv
    // Pb (32M elems) aliases [xb qb] (both dead by softmax time).
    const size_t NEED = (4 * NX + 3 * NW) * sizeof(bf16);

    if (ws_size >= NEED) {
        bf16* xb = (bf16*)d_ws;
        bf16* qb = xb + NX;
        bf16* kb = qb + NX;
        bf16* vt = kb + NX;
        bf16* wq = vt + NX;
        bf16* wk = wq + NW;
        bf16* wv = wk + NW;
        bf16* Pb = xb;                                  // alias over xb+qb

        cvt3_f32_bf16<<<dim3(NW / 2048, 3), blk, 0, stream>>>(
            Wq, wq, Wk, wk, Wv, wv);

        // key -> xb; then k-projection and v^T (both consume xb)
        // grids: BM=256 (y), BN=128 (x)
        cvt_f32_bf16<<<dim3(NX / 2048), blk, 0, stream>>>(key, xb);
        gemm_bt<bf16, 1, 0><<<dim3(8, 64, 1), blk, 0, stream>>>(
            xb, wk, kb, bk, 1024, 1024, 1024, 1024, 0, 0, 0);
        gemm_bt<bf16, 2, 0><<<dim3(16, 4, 8), blk, 0, stream>>>(
            wv, xb, vt, bv, 1024, 1024, 1024, 2048, 0, SB, SB);

        // query -> xb (reuse); q-projection
        cvt_f32_bf16<<<dim3(NX / 2048), blk, 0, stream>>>(query, xb);
        gemm_bt<bf16, 1, 0><<<dim3(8, 64, 1), blk, 0, stream>>>(
            xb, wq, qb, bq, 1024, 1024, 1024, 1024, 0, 0, 0);

        // raw scores fp32 -> cached stores (softmax re-reads from L3)
        gemm_bt<float, 0, 0><<<dim3(16, 8, 8), blk, 0, stream>>>(
            qb, kb, score, nullptr, 1024, 1024, 1024, 2048, SB, SB, SS);

        // masked softmax: fp32 in place + bf16 copy to Pb
        softmax_rows<1><<<dim3(16384), blk, 0, stream>>>(score, mask, Pb);

        // O = P . vt (out is final output -> nt stores)
        gemm_bt<float, 0, 1><<<dim3(8, 8, 8), blk, 0, stream>>>(
            Pb, vt, out, nullptr, 2048, 2048, 2048, 1024, SS, SB, SB);
    } else {
        // fallback: round-2 passing path (fp32 staging, 100.7 MB ws)
        bf16* qb = (bf16*)d_ws;
        bf16* kb = qb + NX;
        bf16* vt = kb + NX;

        gemm_nt<float, float, bf16, 1><<<dim3(8, 128, 1), blk, 0, stream>>>(
            query, Wq, qb, bq, 1024, 1024, 1024, 1024, 0, 0, 0);
        gemm_nt<float, float, bf16, 1><<<dim3(8, 128, 1), blk, 0, stream>>>(
            key, Wk, kb, bk, 1024, 1024, 1024, 1024, 0, 0, 0);
        gemm_nt<float, float, bf16, 2><<<dim3(16, 8, 8), blk, 0, stream>>>(
            Wv, key, vt, bv, 1024, 1024, 1024, 2048, 0, SB, SB);
        gemm_nt<bf16, bf16, float, 0><<<dim3(16, 16, 8), blk, 0, stream>>>(
            qb, kb, score, nullptr, 1024, 1024, 1024, 2048, SB, SB, SS);
        softmax_rows<0><<<dim3(16384), blk, 0, stream>>>(score, mask, nullptr);
        gemm_nt<float, bf16, float, 0><<<dim3(8, 16, 8), blk, 0, stream>>>(
            score, vt, out, nullptr, 2048, 2048, 2048, 1024, SS, SB, SB);
    }
}